// Round 8
// baseline (163.590 us; speedup 1.0000x reference)
//
#include <hip/hip_runtime.h>

// Problem geometry
#define TOT   19267584   // 128*768*14*14 == 128*3*224*224
#define MROWS 25088      // 128*196 patches
#define KD    768        // 3*16*16
#define NPB   196
#define CHW   150528     // 768*196

typedef unsigned int uint;
typedef __attribute__((ext_vector_type(4))) int i32x4;

// workspace layout (bytes)
#define OFF_AQ   0ull              // i8 aq_t[196][12][128][64] = 19,267,584 ; aliased: k1[p][oc]
#define OFF_WQ   19267584ull       // i8 wq_t[6][12][128][64] = 589,824
#define OFF_WSC  19857408ull       // float w_scale[768]
#define OFF_INV  19860480ull       // float inv[768]
#define OFF_SHF  19863552ull       // float shift[768]
#define OFF_PA   19866624ull       // float pA[1176]  (max|x| partials)
#define OFF_PB   19871328ull       // float pB[1176]  (max|y_conv| partials)
#define OFF_SC   19876032ull       // uint sc[4]: s1, s2, s3 bits
#define OFF_CMN  19880736ull       // float cmn[768]
#define OFF_CMX  19883808ull       // float cmx[768]
#define OFF_PMN  19886880ull       // float pmn[768][1568] = 4,816,896
#define OFF_PMX  24703776ull       // float pmx[768][1568] = 4,816,896

__device__ __forceinline__ float wave_max(float v) {
#pragma unroll
  for (int off = 32; off > 0; off >>= 1) v = fmaxf(v, __shfl_xor(v, off));
  return v;
}

// block max, valid in all threads; safe for repeated calls (guarded both sides)
__device__ __forceinline__ float block_max(float v) {
  __shared__ float red[4];
  v = wave_max(v);
  __syncthreads();
  if ((threadIdx.x & 63) == 0) red[threadIdx.x >> 6] = v;
  __syncthreads();
  return fmaxf(fmaxf(red[0], red[1]), fmaxf(red[2], red[3]));
}

// tiled i8 address: [blk128][ks][row128][64]
__device__ __forceinline__ size_t tiled_addr(int row, int k) {
  return (size_t)(row >> 7) * 98304 + (size_t)(k >> 6) * 8192 + ((row & 127) << 6) + (k & 63);
}

// ---------------- K0: fused max|x| partials (blocks 0..1175) + weight quant (1176..1943) ----
__global__ void k_max_wq(const float* __restrict__ x, float* __restrict__ pA,
                         const float* __restrict__ W, const float* __restrict__ gamma,
                         const float* __restrict__ beta, const float* __restrict__ rmean,
                         const float* __restrict__ rvar, signed char* __restrict__ wq,
                         float* __restrict__ wscale, float* __restrict__ inv_,
                         float* __restrict__ shf) {
  if (blockIdx.x < 1176) {
    const int i0 = blockIdx.x * 256 + threadIdx.x;   // 1176*256*16 = TOT/4 exact
    const float4* x4 = (const float4*)x;
    float m = 0.f;
#pragma unroll
    for (int j = 0; j < 16; j += 4) {
      float4 a = x4[i0 + (j + 0) * 301056];
      float4 b = x4[i0 + (j + 1) * 301056];
      float4 c = x4[i0 + (j + 2) * 301056];
      float4 d = x4[i0 + (j + 3) * 301056];
      m = fmaxf(m, fmaxf(fmaxf(fabsf(a.x), fabsf(a.y)), fmaxf(fabsf(a.z), fabsf(a.w))));
      m = fmaxf(m, fmaxf(fmaxf(fabsf(b.x), fabsf(b.y)), fmaxf(fabsf(b.z), fabsf(b.w))));
      m = fmaxf(m, fmaxf(fmaxf(fabsf(c.x), fabsf(c.y)), fmaxf(fabsf(c.z), fabsf(c.w))));
      m = fmaxf(m, fmaxf(fmaxf(fabsf(d.x), fabsf(d.y)), fmaxf(fabsf(d.z), fabsf(d.w))));
    }
    float bm = block_max(m);
    if (threadIdx.x == 0) pA[blockIdx.x] = bm;
  } else {
    const int oc = blockIdx.x - 1176;
    const float* row = W + oc * KD;
    float m = 0.f;
    for (int k = threadIdx.x; k < KD; k += 256) m = fmaxf(m, fabsf(row[k]));
    const float ws_ = block_max(m) / 127.0f;
    for (int k = threadIdx.x; k < KD; k += 256)
      wq[tiled_addr(oc, k)] = (signed char)(int)rintf(row[k] / ws_);
    if (threadIdx.x == 0) {
      wscale[oc] = ws_;
      float iv = gamma[oc] / sqrtf(rvar[oc] + 1e-5f);
      inv_[oc] = iv;
      shf[oc] = __fsub_rn(beta[oc], __fmul_rn(rmean[oc], iv));  // jax: mul then sub, no fma
    }
  }
}

// ---------------- K1: im2col + quant -> TILED aq; folds s0-combine --------------------------
__global__ void k_im2col(const float* __restrict__ x, const float* __restrict__ pA,
                         signed char* __restrict__ aq) {
  float mm = 0.f;
  for (int i = threadIdx.x; i < 1176; i += 256) mm = fmaxf(mm, pA[i]);
  const float ps = block_max(mm) / 127.0f;
  const int u = blockIdx.x * 256 + threadIdx.x;   // u < 1,204,224 = 25088*48 exact
  const int p = u / 48, r = u - p * 48;           // patch, (c,kh) row; k0 = r*16
  const int c = r >> 4, kh = r & 15;
  const int b = p / NPB, pp = p - b * NPB;
  const int ph = pp / 14, pw = pp - ph * 14;
  const float* src = x + (((b * 3 + c) * 224 + ph * 16 + kh) * 224 + pw * 16);
  float4 v0 = *(const float4*)(src);
  float4 v1 = *(const float4*)(src + 4);
  float4 v2 = *(const float4*)(src + 8);
  float4 v3 = *(const float4*)(src + 12);
#define Q8(v) ((int)fminf(fmaxf(rintf((v) / ps), -127.f), 127.f) & 255)
  uint4 o;
  o.x = Q8(v0.x) | (Q8(v0.y) << 8) | (Q8(v0.z) << 16) | ((uint)Q8(v0.w) << 24);
  o.y = Q8(v1.x) | (Q8(v1.y) << 8) | (Q8(v1.z) << 16) | ((uint)Q8(v1.w) << 24);
  o.z = Q8(v2.x) | (Q8(v2.y) << 8) | (Q8(v2.z) << 16) | ((uint)Q8(v2.w) << 24);
  o.w = Q8(v3.x) | (Q8(v3.y) << 8) | (Q8(v3.z) << 16) | ((uint)Q8(v3.w) << 24);
#undef Q8
  // tiled dest: [p>>7][ks=r>>2][p&127][kcol=(r&3)*16]
  *(uint4*)(aq + (size_t)(p >> 7) * 98304 + (size_t)(r >> 2) * 8192 + ((p & 127) << 6) +
            ((r & 3) << 4)) = o;
}

// ---------------- K2: i8 MFMA GEMM, tiled streaming reads, [p][oc] streaming writes ---------
__device__ __forceinline__ void gl_lds16(const void* g, void* l) {
  __builtin_amdgcn_global_load_lds((const __attribute__((address_space(1))) void*)g,
                                   (__attribute__((address_space(3))) void*)l, 16, 0, 0);
}

__global__ __launch_bounds__(256) void k_gemm(const signed char* __restrict__ aq,
                                              const signed char* __restrict__ wq,
                                              const float* __restrict__ bias,
                                              const float* __restrict__ wscale,
                                              const float* __restrict__ pA,
                                              float* __restrict__ y,
                                              float* __restrict__ pB) {
  __shared__ __align__(16) signed char lA[2][8192];   // 128 rows x 64 K (i8), dbuf
  __shared__ __align__(16) signed char lB[2][8192];
  const int tid = threadIdx.x, lane = tid & 63, wv = tid >> 6;
  // XCD-aware swizzle (1176 = 8*147, bijective) + bn-inner: 6 consecutive blocks share A-tile
  const int bsw = (blockIdx.x & 7) * 147 + (blockIdx.x >> 3);
  const int bm = bsw / 6, bn = bsw - 6 * (bsw / 6);
  const int wr = wv >> 1, wc = wv & 1;               // 2x2 waves, 64x64 each

  // s0-combine
  float mm = 0.f;
  for (int i = tid; i < 1176; i += 256) mm = fmaxf(mm, pA[i]);
  const float ps_ = block_max(mm) / 127.0f;

  // staging: tile chunk = 1KB contiguous; rule-21 swizzle pair (source XOR, LDS linear)
  const int ci0 = wv * 2, ci1 = wv * 2 + 1;
  const int lo = ((lane >> 2) << 6) + (((lane & 3) ^ ((lane >> 3) & 3)) << 4);
  const signed char* gA0 = aq + (size_t)bm * 98304 + ci0 * 1024 + lo;
  const signed char* gA1 = aq + (size_t)bm * 98304 + ci1 * 1024 + lo;
  const signed char* gB0 = wq + (size_t)bn * 98304 + ci0 * 1024 + lo;
  const signed char* gB1 = wq + (size_t)bn * 98304 + ci1 * 1024 + lo;

  i32x4 acc[4][4];
#pragma unroll
  for (int m = 0; m < 4; ++m)
#pragma unroll
    for (int n = 0; n < 4; ++n) acc[m][n] = (i32x4){0, 0, 0, 0};

  const int rbase = lane & 15;
  // read k-offset: wanted piece (lane>>4) XOR row-swizzle ((lane>>1)&3); 2-way conflicts
  const int kg = ((lane >> 4) << 4) ^ (((lane >> 1) & 3) << 4);

#define STAGE(T, B)                                   \
  {                                                   \
    const size_t kk_ = (size_t)(T) * 8192;            \
    gl_lds16(gA0 + kk_, &lA[B][ci0 * 1024]);          \
    gl_lds16(gA1 + kk_, &lA[B][ci1 * 1024]);          \
    gl_lds16(gB0 + kk_, &lB[B][ci0 * 1024]);          \
    gl_lds16(gB1 + kk_, &lB[B][ci1 * 1024]);          \
  }

  STAGE(0, 0)
  __syncthreads();

  int cur = 0;
  for (int t = 0; t < 12; ++t) {
    if (t < 11) STAGE(t + 1, cur ^ 1)                // prefetch next K-tile
    i32x4 af[4], bfr[4];
#pragma unroll
    for (int m = 0; m < 4; ++m)
      af[m] = *(const i32x4*)&lA[cur][(wr * 64 + m * 16 + rbase) * 64 + kg];
#pragma unroll
    for (int n = 0; n < 4; ++n)
      bfr[n] = *(const i32x4*)&lB[cur][(wc * 64 + n * 16 + rbase) * 64 + kg];
#pragma unroll
    for (int m = 0; m < 4; ++m)
#pragma unroll
      for (int n = 0; n < 4; ++n)
        acc[m][n] = __builtin_amdgcn_mfma_i32_16x16x64_i8(bfr[n], af[m], acc[m][n], 0, 0, 0);
    __syncthreads();   // drains vmcnt (prefetch landed); buffers swap safely
    cur ^= 1;
  }
#undef STAGE

  // epilogue (operand-swapped C layout): lane holds 4 consecutive oc (reg j), p = lane&15
  // y layout [p][oc]: fully contiguous streaming writes
  float lmax = 0.f;
#pragma unroll
  for (int n = 0; n < 4; ++n) {
    const int ocb = bn * 128 + wc * 64 + n * 16 + ((lane >> 4) << 2);
    const float4 ws4 = *(const float4*)&wscale[ocb];
    const float4 b4 = *(const float4*)&bias[ocb];
    const float c0 = ws4.x * ps_, c1 = ws4.y * ps_, c2 = ws4.z * ps_, c3 = ws4.w * ps_;
    const float i0 = rintf(b4.x / c0), i1 = rintf(b4.y / c1);
    const float i2 = rintf(b4.z / c2), i3 = rintf(b4.w / c3);
#pragma unroll
    for (int m = 0; m < 4; ++m) {
      const int p = bm * 128 + wr * 64 + m * 16 + rbase;
      float4 o;
      o.x = ((float)acc[m][n][0] + i0) * c0;
      o.y = ((float)acc[m][n][1] + i1) * c1;
      o.z = ((float)acc[m][n][2] + i2) * c2;
      o.w = ((float)acc[m][n][3] + i3) * c3;
      lmax = fmaxf(lmax, fmaxf(fmaxf(fabsf(o.x), fabsf(o.y)), fmaxf(fabsf(o.z), fabsf(o.w))));
      *(float4*)(y + (size_t)p * 768 + ocb) = o;
    }
  }
  float bm_ = block_max(lmax);
  if (tid == 0) pB[blockIdx.x] = bm_;
}

// ---------------- K3: gelu pass on [p][oc]: write k1, thread-exclusive channel min/max ------
__global__ void k_gelu(const float* __restrict__ y, const float* __restrict__ pB,
                       signed char* __restrict__ k1, float* __restrict__ pmn,
                       float* __restrict__ pmx) {
  const int b = blockIdx.x;            // 1568 blocks x 16 patch rows
  const int t = threadIdx.x;
  float mm = 0.f;
  for (int i = t; i < 1176; i += 256) mm = fmaxf(mm, pB[i]);
  const float s1 = block_max(mm) / 127.0f;
  __shared__ float tab[255];
  for (int i = t; i < 255; i += 256) {
    float y1 = (float)(i - 127) * s1;
    float e = erff(y1 * 0.70710678118654752f);
    tab[i] = (y1 * (e + 1.0f)) * 0.5f;
  }
  __syncthreads();
  float mn0 = 1e30f, mx0 = -1e30f, mn1 = 1e30f, mx1 = -1e30f, mn2 = 1e30f, mx2 = -1e30f;
  const float* yb = y + (size_t)b * 16 * 768 + t;
  signed char* kb = k1 + (size_t)b * 16 * 768 + t;
#pragma unroll 4
  for (int row = 0; row < 16; ++row) {
    const float* yr = yb + row * 768;
    float v0 = yr[0], v1 = yr[256], v2 = yr[512];
    int a = (int)fminf(fmaxf(rintf(v0 / s1), -127.f), 127.f);
    int bq = (int)fminf(fmaxf(rintf(v1 / s1), -127.f), 127.f);
    int cq = (int)fminf(fmaxf(rintf(v2 / s1), -127.f), 127.f);
    signed char* kr = kb + row * 768;
    kr[0] = (signed char)a;
    kr[256] = (signed char)bq;
    kr[512] = (signed char)cq;
    float g0 = tab[a + 127], g1 = tab[bq + 127], g2 = tab[cq + 127];
    mn0 = fminf(mn0, g0); mx0 = fmaxf(mx0, g0);
    mn1 = fminf(mn1, g1); mx1 = fmaxf(mx1, g1);
    mn2 = fminf(mn2, g2); mx2 = fmaxf(mx2, g2);
  }
  pmn[(size_t)t * 1568 + b] = mn0;         pmx[(size_t)t * 1568 + b] = mx0;
  pmn[(size_t)(t + 256) * 1568 + b] = mn1; pmx[(size_t)(t + 256) * 1568 + b] = mx1;
  pmn[(size_t)(t + 512) * 1568 + b] = mn2; pmx[(size_t)(t + 512) * 1568 + b] = mx2;
}

// ---------------- K4: per-channel reduce of gelu partials ----------------------------------
__global__ void k_chred(const float* __restrict__ pmn, const float* __restrict__ pmx,
                        float* __restrict__ cmn, float* __restrict__ cmx) {
  const int c = blockIdx.x;
  float lo = 1e30f, hi = -1e30f;
  for (int i = threadIdx.x; i < 1568; i += 256) {
    lo = fminf(lo, pmn[(size_t)c * 1568 + i]);
    hi = fmaxf(hi, pmx[(size_t)c * 1568 + i]);
  }
  float bhi = block_max(hi);
  float blo = -block_max(-lo);
  if (threadIdx.x == 0) { cmn[c] = blo; cmx[c] = bhi; }
}

// ---------------- K5: scalars s1, s2, s3 (monotone chain on channel extremes => exact) -----
__global__ void k_scales(const float* __restrict__ pB, const float* __restrict__ cmn,
                         const float* __restrict__ cmx, const float* __restrict__ inv_,
                         const float* __restrict__ shf, uint* __restrict__ sc) {
  const int t = threadIdx.x;
  float m = 0.f;
  for (int i = t; i < 1176; i += 256) m = fmaxf(m, pB[i]);
  const float s1 = block_max(m) / 127.0f;
  float m2 = 0.f;
  for (int c = t; c < 768; c += 256)
    m2 = fmaxf(m2, fmaxf(fabsf(cmn[c]), fabsf(cmx[c])));
  const float s2 = block_max(m2) / 127.0f;
  float m4 = 0.f;
  for (int c = t; c < 768; c += 256) {
    float iv = inv_[c], sh = shf[c];
    float a = fminf(fmaxf(rintf(cmn[c] / s2), -127.f), 127.f) * s2;
    float b = fminf(fmaxf(rintf(cmx[c] / s2), -127.f), 127.f) * s2;
    float ya = __fadd_rn(__fmul_rn(a, iv), sh);
    float yb = __fadd_rn(__fmul_rn(b, iv), sh);
    m4 = fmaxf(m4, fmaxf(fabsf(ya), fabsf(yb)));
  }
  const float s3 = block_max(m4) / 127.0f;
  if (t == 0) {
    sc[0] = __float_as_uint(s1);
    sc[1] = __float_as_uint(s2);
    sc[2] = __float_as_uint(s3);
  }
}

// ---------------- K6: final: k1[p][oc] -> out NCHW, contiguous 256B output runs ------------
__global__ void k_final(const signed char* __restrict__ k1, const uint* __restrict__ sc,
                        const float* __restrict__ inv_, const float* __restrict__ shf,
                        float* __restrict__ out) {
  const float s1 = __uint_as_float(sc[0]);
  const float s2 = __uint_as_float(sc[1]);
  const float s3 = __uint_as_float(sc[2]);
  __shared__ float tab[255];
  for (int i = threadIdx.x; i < 255; i += 256) {
    float y1 = (float)(i - 127) * s1;
    float e = erff(y1 * 0.70710678118654752f);
    float y2 = (y1 * (e + 1.0f)) * 0.5f;
    float q2 = fminf(fmaxf(rintf(y2 / s2), -127.f), 127.f);
    tab[i] = q2 * s2;
  }
  __syncthreads();
  const int img = blockIdx.x / 12, ocg = blockIdx.x - 12 * (blockIdx.x / 12);
  const int oc0 = ocg * 64;
  const int g = threadIdx.x & 15;
  const signed char* kbase = k1 + (size_t)img * 196 * 768;
  float* obase = out + (size_t)img * CHW;
#define FIN4(Q, OC, IV, SH)                                                  \
  {                                                                          \
    const signed char* kp = kbase + (size_t)(Q)*768 + (OC);                  \
    int a = kp[0], b = kp[768], c = kp[1536], d = kp[2304];                  \
    float fa = __fadd_rn(__fmul_rn(tab[a + 127], (IV)), (SH));               \
    float fb = __fadd_rn(__fmul_rn(tab[b + 127], (IV)), (SH));               \
    float fc = __fadd_rn(__fmul_rn(tab[c + 127], (IV)), (SH));               \
    float fd = __fadd_rn(__fmul_rn(tab[d + 127], (IV)), (SH));               \
    float4 o;                                                                \
    o.x = fminf(fmaxf(rintf(fa / s3), -127.f), 127.f) * s3;                  \
    o.y = fminf(fmaxf(rintf(fb / s3), -127.f), 127.f) * s3;                  \
    o.z = fminf(fmaxf(rintf(fc / s3), -127.f), 127.f) * s3;                  \
    o.w = fminf(fmaxf(rintf(fd / s3), -127.f), 127.f) * s3;                  \
    *(float4*)(obase + (size_t)(OC)*196 + (Q)) = o;                          \
  }
#pragma unroll
  for (int ocs = 0; ocs < 4; ++ocs) {
    const int oc = oc0 + ocs * 16 + (threadIdx.x >> 4);
    const float iv = inv_[oc], sh = shf[oc];
    FIN4(g * 4, oc, iv, sh)
    FIN4(64 + g * 4, oc, iv, sh)
    FIN4(128 + g * 4, oc, iv, sh)
    if (g == 0) FIN4(192, oc, iv, sh)
  }
#undef FIN4
  if (blockIdx.x == 0 && threadIdx.x == 0) out[TOT] = s3;  // act_scale
}

extern "C" void kernel_launch(void* const* d_in, const int* in_sizes, int n_in,
                              void* d_out, int out_size, void* d_ws, size_t ws_size,
                              hipStream_t stream) {
  const float* x     = (const float*)d_in[0];
  const float* W     = (const float*)d_in[1];
  const float* bias  = (const float*)d_in[2];
  const float* gamma = (const float*)d_in[3];
  const float* beta  = (const float*)d_in[4];
  const float* rmean = (const float*)d_in[5];
  const float* rvar  = (const float*)d_in[6];
  float* out = (float*)d_out;
  char* ws = (char*)d_ws;

  signed char* aq  = (signed char*)(ws + OFF_AQ);
  signed char* wq  = (signed char*)(ws + OFF_WQ);
  float* wsc  = (float*)(ws + OFF_WSC);
  float* inv_ = (float*)(ws + OFF_INV);
  float* shf  = (float*)(ws + OFF_SHF);
  float* pA   = (float*)(ws + OFF_PA);
  float* pB   = (float*)(ws + OFF_PB);
  uint*  sc   = (uint*)(ws + OFF_SC);
  float* cmn  = (float*)(ws + OFF_CMN);
  float* cmx  = (float*)(ws + OFF_CMX);
  float* pmn  = (float*)(ws + OFF_PMN);
  float* pmx  = (float*)(ws + OFF_PMX);
  signed char* k1 = (signed char*)(ws + OFF_AQ);  // aliases aq (dead after GEMM)

  k_max_wq<<<1944, 256, 0, stream>>>(x, pA, W, gamma, beta, rmean, rvar, wq, wsc, inv_, shf);
  k_im2col<<<4704, 256, 0, stream>>>(x, pA, aq);
  k_gemm<<<1176, 256, 0, stream>>>(aq, wq, bias, wsc, pA, out, pB);
  k_gelu<<<1568, 256, 0, stream>>>(out, pB, k1, pmn, pmx);
  k_chred<<<768, 256, 0, stream>>>(pmn, pmx, cmn, cmx);
  k_scales<<<1, 256, 0, stream>>>(pB, cmn, cmx, inv_, shf, sc);
  k_final<<<1536, 256, 0, stream>>>(k1, sc, inv_, shf, out);
}